// Round 1
// baseline (2463.483 us; speedup 1.0000x reference)
//
#include <hip/hip_runtime.h>
#include <math.h>

static constexpr int TT = 512;   // sequence length
static constexpr int BB = 256;   // batch

// One workgroup per batch row; persistent loop over T with LDS-only sync.
// Thread (s, c) owns column c of z (c in [0,4H)) and k-slice s of the fused
// dot  z[c] = sum_k [x_t | h]_k * W[k][c],  weights held in registers.
// Gate threads (tid < H) do the elementwise LSTM cell update.
template<int DIN, int H, int NS, bool HAS_X, bool WRITE_SEQ, bool WRITE_LAST, bool FUSE_DENSE>
__global__ void __launch_bounds__(4*H*NS)
lstm_layer(const float* __restrict__ xin,    // [B,T,DIN] if HAS_X else [B,DIN] (constant input)
           const float* __restrict__ Wk,     // [DIN,4H]
           const float* __restrict__ Wr,     // [H,4H]
           const float* __restrict__ bias,   // [4H]
           float* __restrict__ seq_out,      // [B,T,H]   (WRITE_SEQ)
           float* __restrict__ last_out,     // [B,H]     (WRITE_LAST)
           const float* __restrict__ Wout,   // [H,64]    (FUSE_DENSE)
           const float* __restrict__ boutp,  // [64]      (FUSE_DENSE)
           float* __restrict__ dense_out)    // [B,T,64]  (FUSE_DENSE)
{
  constexpr int C4H  = 4*H;
  constexpr int NTH  = C4H*NS;
  constexpr int KTOT = HAS_X ? (DIN + H) : H;
  constexpr int KS   = KTOT / NS;
  constexpr int XOFF = HAS_X ? DIN : 0;
  constexpr int XH   = XOFF + H;

  const int tid = (int)threadIdx.x;
  const int b   = (int)blockIdx.x;
  const int s   = tid / C4H;
  const int c   = tid % C4H;

  __shared__ __align__(16) float xh[XH];          // [x_t (DIN) | h (H)]
  __shared__ float zp[NS*C4H];                    // partial dots
  __shared__ float zl[HAS_X ? 1 : DIN];           // constant-input row
  __shared__ float wout_s[FUSE_DENSE ? (H*64) : 1];
  __shared__ float dp[FUSE_DENSE ? (16*64) : 1];

  // ---- one-time: weight columns into registers (coalesced along c) ----
  float w[KS];
  #pragma unroll
  for (int i = 0; i < KS; ++i) {
    const int k = s*KS + i;
    const float* src;
    if (HAS_X) src = (k < DIN) ? (Wk + (size_t)k*C4H) : (Wr + (size_t)(k-DIN)*C4H);
    else       src = Wr + (size_t)k*C4H;
    w[i] = src[c];
  }

  float bi=0.f, bf=0.f, bg=0.f, bo=0.f, cst=0.f;
  if (tid < H) {
    bi = bias[tid]; bf = bias[H+tid]; bg = bias[2*H+tid]; bo = bias[3*H+tid];
  }
  float boutr = 0.f;
  if constexpr (FUSE_DENSE) { if (tid < 64) boutr = boutp[tid]; }

  // ---- init LDS ----
  for (int i = tid; i < XH; i += NTH) xh[i] = 0.f;   // h0 = 0 (x part overwritten below)
  if constexpr (!HAS_X) { if (tid < DIN) zl[tid] = xin[(size_t)b*DIN + tid]; }
  if constexpr (FUSE_DENSE) { for (int i = tid; i < H*64; i += NTH) wout_s[i] = Wout[i]; }
  __syncthreads();

  // constant-input contribution folded into the s==0 partial
  float zin = 0.f;
  if constexpr (!HAS_X) {
    if (s == 0) {
      #pragma unroll
      for (int k = 0; k < DIN; ++k) zin = fmaf(zl[k], Wk[(size_t)k*C4H + c], zin);
    }
  }
  if constexpr (HAS_X) {
    if (tid < DIN) xh[tid] = xin[((size_t)b*TT)*DIN + tid];  // stage x_0
  }
  __syncthreads();

  for (int t = 0; t < TT; ++t) {
    // ---- phase A: fused input+recurrent dot, K split NS ways ----
    float acc = zin;
    #pragma unroll
    for (int i = 0; i < KS; ++i) acc = fmaf(xh[s*KS + i], w[i], acc);
    zp[s*C4H + c] = acc;
    __syncthreads();

    // ---- phase B: gates + state update (threads < H); stage x_{t+1} ----
    if (tid < H) {
      float vi=bi, vf=bf, vg=bg, vo=bo;
      #pragma unroll
      for (int ss = 0; ss < NS; ++ss) {
        vi += zp[ss*C4H + tid];
        vf += zp[ss*C4H + H   + tid];
        vg += zp[ss*C4H + 2*H + tid];
        vo += zp[ss*C4H + 3*H + tid];
      }
      const float gi = 1.f/(1.f + expf(-vi));
      const float gf = 1.f/(1.f + expf(-vf));
      const float go = 1.f/(1.f + expf(-vo));
      const float gg = fmaxf(vg, 0.f);          // activation = relu
      cst = fmaf(gf, cst, gi*gg);               // c = f*c + i*g
      const float h = go * fmaxf(cst, 0.f);     // h = o * relu(c)
      xh[XOFF + tid] = h;
      if constexpr (WRITE_SEQ) seq_out[((size_t)b*TT + t)*H + tid] = h;
      if constexpr (WRITE_LAST) { if (t == TT-1) last_out[(size_t)b*H + tid] = h; }
    }
    if constexpr (HAS_X) {
      const int st = tid - C4H;                 // threads [C4H, C4H+DIN): idle in B otherwise
      if (st >= 0 && st < DIN && (t+1) < TT)
        xh[st] = xin[((size_t)b*TT + (t+1))*DIN + st];
    }
    __syncthreads();

    // ---- fused TimeDistributed Dense (dec2 only): out[b,t,:] = h @ Wout + bout ----
    if constexpr (FUSE_DENSE) {
      {
        const int f = tid & 63, sl = tid >> 6;  // 64 cols x 16 k-slices of 8
        float a = 0.f;
        #pragma unroll
        for (int i = 0; i < 8; ++i)
          a = fmaf(xh[XOFF + sl*8 + i], wout_s[(sl*8 + i)*64 + f], a);
        dp[sl*64 + f] = a;
      }
      __syncthreads();
      if (tid < 64) {
        float o = boutr;
        #pragma unroll
        for (int sl = 0; sl < 16; ++sl) o += dp[sl*64 + tid];
        dense_out[((size_t)b*TT + t)*64 + tid] = o;
      }
      // no trailing barrier needed: next phase-A barrier orders dp reuse
    }
  }
}

extern "C" void kernel_launch(void* const* d_in, const int* in_sizes, int n_in,
                              void* d_out, int out_size, void* d_ws, size_t ws_size,
                              hipStream_t stream) {
  const float* x    = (const float*)d_in[0];
  const float* Wk1  = (const float*)d_in[1];
  const float* Wr1  = (const float*)d_in[2];
  const float* b1   = (const float*)d_in[3];
  const float* Wk2  = (const float*)d_in[4];
  const float* Wr2  = (const float*)d_in[5];
  const float* b2   = (const float*)d_in[6];
  const float* Wd1k = (const float*)d_in[7];
  const float* Wd1r = (const float*)d_in[8];
  const float* bd1  = (const float*)d_in[9];
  const float* Wd2k = (const float*)d_in[10];
  const float* Wd2r = (const float*)d_in[11];
  const float* bd2  = (const float*)d_in[12];
  const float* Wout = (const float*)d_in[13];
  const float* bout = (const float*)d_in[14];
  float* out = (float*)d_out;

  // workspace: h1_seq [B,T,128] (64MB), reused by d1_seq [B,T,64] (32MB); z [B,64] after it
  const size_t h1_elems = (size_t)BB * TT * 128;
  const size_t need = (h1_elems + (size_t)BB*64) * sizeof(float);
  if (ws_size < need) return;  // fail loudly in validation rather than corrupt memory
  float* h1 = (float*)d_ws;
  float* z  = h1 + h1_elems;
  float* d1 = h1;  // h1 dead after enc2

  // encoder layer 1: 64 -> 128, return sequences
  lstm_layer<64,128,2,true, true, false,false><<<BB,1024,0,stream>>>(x,  Wk1,  Wr1,  b1,  h1, nullptr, nullptr, nullptr, nullptr);
  // encoder layer 2: 128 -> 64, return last state
  lstm_layer<128,64,2,true, false,true, false><<<BB, 512,0,stream>>>(h1, Wk2,  Wr2,  b2,  nullptr, z, nullptr, nullptr, nullptr);
  // decoder layer 1: constant input z (RepeatVector), 64 -> 64
  lstm_layer<64, 64,2,false,true, false,false><<<BB, 512,0,stream>>>(z,  Wd1k, Wd1r, bd1, d1, nullptr, nullptr, nullptr, nullptr);
  // decoder layer 2: 64 -> 128, fused TimeDistributed Dense 128 -> 64
  lstm_layer<64,128,2,true, false,false,true ><<<BB,1024,0,stream>>>(d1, Wd2k, Wd2r, bd2, nullptr, nullptr, Wout, bout, out);
}